// Round 15
// baseline (611.410 us; speedup 1.0000x reference)
//
#include <hip/hip_runtime.h>
#include <hip/hip_cooperative_groups.h>
namespace cg = cooperative_groups;

typedef __attribute__((ext_vector_type(4))) float  f32x4;
typedef __attribute__((ext_vector_type(2))) float  f32x2;
typedef __attribute__((ext_vector_type(8))) short  s16x8;
typedef __attribute__((ext_vector_type(4))) float  f4v;
typedef __attribute__((ext_vector_type(4))) int    i32x4;

#define MFMA_BF16 __builtin_amdgcn_mfma_f32_16x16x32_bf16
#define SENT 0x7fffffff

#if defined(__has_builtin)
#if __has_builtin(__builtin_amdgcn_cvt_pk_fp8_f32) && __has_builtin(__builtin_amdgcn_cvt_pk_f32_fp8)
#define HW8 1
#endif
#endif

// ---------- helpers ----------
__device__ __forceinline__ short f2bf(float f) {
  unsigned u = __builtin_bit_cast(unsigned, f);
  u += 0x7fffu + ((u >> 16) & 1u);
  return (short)(u >> 16);
}
__device__ __forceinline__ float bf2f(short s) {
  unsigned u = ((unsigned)(unsigned short)s) << 16;
  return __builtin_bit_cast(float, u);
}
__device__ __forceinline__ s16x8 cvt8(f4v f0, f4v f1) {
  s16x8 r;
  r[0] = f2bf(f0[0]); r[1] = f2bf(f0[1]); r[2] = f2bf(f0[2]); r[3] = f2bf(f0[3]);
  r[4] = f2bf(f1[0]); r[5] = f2bf(f1[1]); r[6] = f2bf(f1[2]); r[7] = f2bf(f1[3]);
  return r;
}
// HW packed bf16 convert (gfx950)
__device__ __forceinline__ unsigned cvtpk_bf16(float a, float b) {
  unsigned r;
  asm("v_cvt_pk_bf16_f32 %0, %1, %2" : "=v"(r) : "v"(a), "v"(b));
  return r;
}
// manual fp8 e4m3fn (fallback when no HW builtin)
__device__ __forceinline__ unsigned f2fp8(float x) {
  unsigned u = __builtin_bit_cast(unsigned, x);
  unsigned s = (u >> 24) & 0x80u;
  unsigned au = u & 0x7fffffffu;
  if (au < 0x3C800000u) return s;
  unsigned biased = au - 0x3C000000u;
  unsigned val = biased >> 20;
  unsigned rem = biased & 0xFFFFFu;
  val += (rem > 0x80000u) || (rem == 0x80000u && (val & 1u));
  if (val > 0x7Eu) val = 0x7Eu;
  return s | val;
}
__device__ __forceinline__ float fp8tof(unsigned b) {
  unsigned em = b & 0x7fu;
  unsigned f = ((em + 960u) << 20) | ((b & 0x80u) << 24);
  return (em < 8u) ? 0.f : __builtin_bit_cast(float, f);
}
__device__ __forceinline__ unsigned char enc_fp8(float x) {
#ifdef HW8
  return (unsigned char)(__builtin_amdgcn_cvt_pk_fp8_f32(x, x, 0u, false) & 0xffu);
#else
  return (unsigned char)f2fp8(x);
#endif
}
// pack 4 floats -> 4 fp8 bytes in one dword
__device__ __forceinline__ unsigned enc_fp8x4(f4v v) {
#ifdef HW8
  unsigned u = __builtin_amdgcn_cvt_pk_fp8_f32(v[0], v[1], 0u, false);
  u = __builtin_amdgcn_cvt_pk_fp8_f32(v[2], v[3], u, true);
  return u;
#else
  return f2fp8(v[0]) | (f2fp8(v[1]) << 8) | (f2fp8(v[2]) << 16) | (f2fp8(v[3]) << 24);
#endif
}
__device__ __forceinline__ void dec_fp8x4(unsigned d, float* f) {
#ifdef HW8
  f32x2 lo = __builtin_amdgcn_cvt_pk_f32_fp8(d, false);
  f32x2 hi = __builtin_amdgcn_cvt_pk_f32_fp8(d, true);
  f[0] = lo[0]; f[1] = lo[1]; f[2] = hi[0]; f[3] = hi[1];
#else
#pragma unroll
  for (int j = 0; j < 4; ++j) f[j] = fp8tof((d >> (8 * j)) & 0xffu);
#endif
}

// ---------- weight prep + optional zeroing of out & cnt ----------
__global__ __launch_bounds__(256) void prep_weights(
    const float* __restrict__ W1, const float* __restrict__ W2,
    short* __restrict__ wp, float* __restrict__ out, int outN4,
    int* __restrict__ cnt, int NN) {
  int t = blockIdx.x * 256 + threadIdx.x;
  int total = gridDim.x * 256;
  if (out) {
    f32x4* o4 = reinterpret_cast<f32x4*>(out);
    for (int i = t; i < outN4; i += total) o4[i] = (f32x4){0.f, 0.f, 0.f, 0.f};
  }
  if (cnt) {
    for (int i = t; i < NN; i += total) cnt[i] = 0;
  }
  int chunk = t >> 6, l = t & 63;
  if (chunk >= 104) return;
  int q = l >> 4, c = l & 15;
  s16x8 v;
  if (chunk < 72) {
    int kk = chunk >> 3, nt = chunk & 7;
    int k0 = kk * 32 + q * 8, n = nt * 16 + c;
#pragma unroll
    for (int j = 0; j < 8; ++j) {
      int k = k0 + j;
      v[j] = (k < 272) ? f2bf(W1[k * 128 + n]) : (short)0;
    }
    *reinterpret_cast<s16x8*>(wp + (size_t)chunk * 512 + l * 8) = v;
  } else {
    int c2 = chunk - 72;
    int kk = c2 >> 3, nt = c2 & 7;
    int k0 = kk * 32 + q * 8, n = nt * 16 + c;
#pragma unroll
    for (int j = 0; j < 8; ++j) v[j] = f2bf(W2[(k0 + j) * 128 + n]);
    *reinterpret_cast<s16x8*>(wp + 36864 + (size_t)c2 * 512 + l * 8) = v;
  }
}

// ---------- fused dense G + edge histogram (r4 verified) ----------
// G layout per node: 384 B = [128 bf16 G1 (row half)] [128 B fp8 G2 (col half, permuted)]
#define NB_H 512
__global__ __launch_bounds__(256) void k_gh(
    const float* __restrict__ h, const short* __restrict__ wp,
    short* __restrict__ Gs, const int* __restrict__ ei,
    int* __restrict__ cnt, int NN, int NB_G, int E) {
  if ((int)blockIdx.x >= NB_G) {
    int i = ((int)blockIdx.x - NB_G) * 256 + threadIdx.x;
    for (; i < E; i += NB_H * 256) atomicAdd(&cnt[ei[i]], 1);
    return;
  }
  const int tid = threadIdx.x;
  const int w = tid >> 6, l = tid & 63;
  const int q = l >> 4, c = l & 15;
  const int nb = blockIdx.x * 64 + w * 16;

  f32x4 acc[16];
#pragma unroll
  for (int nt = 0; nt < 16; ++nt) acc[nt] = (f32x4){0.f, 0.f, 0.f, 0.f};

#pragma unroll
  for (int kk = 0; kk < 4; ++kk) {
    int node = nb + c; if (node >= NN) node = NN - 1;
    const float* src = h + (size_t)node * 128 + kk * 32 + q * 8;
    s16x8 a = cvt8(*reinterpret_cast<const f4v*>(src),
                   *reinterpret_cast<const f4v*>(src + 4));
#pragma unroll
    for (int nt2 = 0; nt2 < 16; ++nt2) {
      int kkg = kk + ((nt2 >= 8) ? 4 : 0);
      int chunk = kkg * 8 + (nt2 & 7);
      s16x8 b = *reinterpret_cast<const s16x8*>(wp + (size_t)chunk * 512 + l * 8);
      acc[nt2] = MFMA_BF16(a, b, acc[nt2], 0, 0, 0);
    }
  }
  unsigned char* Gb = (unsigned char*)Gs;
#pragma unroll
  for (int nt2 = 0; nt2 < 16; ++nt2)
#pragma unroll
    for (int r = 0; r < 4; ++r) {
      int node = nb + q * 4 + r;
      if (node < NN) {
        if (nt2 < 8) {
          Gs[(size_t)node * 192 + nt2 * 16 + c] = f2bf(acc[nt2][r]);
        } else {
          int n7 = nt2 - 8;
          int addr = ((n7 & 1) * 2 + (c >> 3)) * 32 + (n7 >> 1) * 8 + (c & 7);
          Gb[(size_t)node * 384 + 256 + addr] = enc_fp8(acc[nt2][r]);
        }
      }
    }
}

// ---------- cooperative fused scan + scatter + out-zeroing ----------
// Blocks [0, P): 256-wide LDS scan of cnt -> exclusive prefix (2 grid syncs).
// Blocks [P, grid): zero `out` during phase A (free overlap).
// Phase C (all blocks): scatter edges + fp8 bond permute (r13-verified logic).
__global__ __launch_bounds__(256) void k_sss(
    const int* __restrict__ ei, int* __restrict__ cnt, int* __restrict__ par,
    int* __restrict__ rc, unsigned* __restrict__ bond8,
    const float* __restrict__ bond, float* __restrict__ out,
    int E, int NN, int outN4) {
  cg::grid_group grid = cg::this_grid();
  __shared__ int ps[256];
  __shared__ int red[4];
  const int t = threadIdx.x, bid = blockIdx.x;
  const int P = (NN + 255) >> 8;
  const int idx = bid * 256 + t;
  int v = 0;
  if (bid < P) {
    v = (idx < NN) ? cnt[idx] : 0;
    ps[t] = v;
    __syncthreads();
    for (int d = 1; d < 256; d <<= 1) {
      int u = (t >= d) ? ps[t - d] : 0;
      __syncthreads(); ps[t] += u; __syncthreads();
    }
    if (t == 255) par[bid] = ps[255];
  } else {
    f32x4* o4 = reinterpret_cast<f32x4*>(out);
    int nb = gridDim.x - P;
    for (int i = (bid - P) * 256 + t; i < outN4; i += nb * 256)
      o4[i] = (f32x4){0.f, 0.f, 0.f, 0.f};
  }
  grid.sync();
  if (bid < P) {
    int pv = (t < bid) ? par[t] : 0;      // P <= 256, t covers all partials
#pragma unroll
    for (int d = 1; d < 64; d <<= 1) pv += __shfl_xor(pv, d);
    if ((t & 63) == 0) red[t >> 6] = pv;
    __syncthreads();
    int base = red[0] + red[1] + red[2] + red[3];
    if (idx < NN) cnt[idx] = ps[t] - v + base;
  }
  grid.sync();
  // scatter phase (grid-stride)
  const int stride = gridDim.x * 256;
  for (int i = bid * 256 + t; i < E; i += stride) {
    int r = ei[i], c = ei[(size_t)E + i];
    int pos = atomicAdd(&cnt[r], 1);
    rc[pos] = r | (c << 16);
    const f4v* b4 = reinterpret_cast<const f4v*>(bond + (size_t)i * 16);
    i32x4 o;
    o[0] = (int)enc_fp8x4(b4[0]);
    o[1] = (int)enc_fp8x4(b4[1]);
    o[2] = (int)enc_fp8x4(b4[2]);
    o[3] = (int)enc_fp8x4(b4[3]);
    *reinterpret_cast<i32x4*>(bond8 + (size_t)pos * 4) = o;
  }
}

// ---------- fallback scan/scatter (r13/r14 verified) ----------
__global__ __launch_bounds__(1024) void k_s1(const int* __restrict__ cnt,
                                             int* __restrict__ partial, int NN) {
  __shared__ int red[16];
  int t = threadIdx.x, idx = blockIdx.x * 1024 + t;
  int v = (idx < NN) ? cnt[idx] : 0;
#pragma unroll
  for (int d = 1; d < 64; d <<= 1) v += __shfl_xor(v, d);
  if ((t & 63) == 0) red[t >> 6] = v;
  __syncthreads();
  if (t == 0) {
    int s = 0;
#pragma unroll
    for (int i = 0; i < 16; ++i) s += red[i];
    partial[blockIdx.x] = s;
  }
}
__global__ __launch_bounds__(1024) void k_s3m(int* __restrict__ cnt,
                                              const int* __restrict__ partial,
                                              int NN) {
  __shared__ int ps[1024];
  __shared__ int pbuf[64];
  __shared__ int base_s;
  int t = threadIdx.x, bid = blockIdx.x, idx = bid * 1024 + t;
  if (t < 64) pbuf[t] = (t < bid) ? partial[t] : 0;
  int v = (idx < NN) ? cnt[idx] : 0;
  ps[t] = v;
  __syncthreads();
  if (t == 0) {
    int b = 0;
#pragma unroll
    for (int j = 0; j < 64; ++j) b += pbuf[j];
    base_s = b;
  }
  for (int d = 1; d < 1024; d <<= 1) {
    int u = (t >= d) ? ps[t - d] : 0;
    __syncthreads(); ps[t] += u; __syncthreads();
  }
  if (idx < NN) cnt[idx] = ps[t] - v + base_s;
}
__global__ void k_scatter13(const int* __restrict__ ei, int* __restrict__ cnt,
                            int* __restrict__ rc, unsigned* __restrict__ bond8,
                            const float* __restrict__ bond, int E) {
  int i = blockIdx.x * blockDim.x + threadIdx.x;
  int stride = gridDim.x * blockDim.x;
  for (; i < E; i += stride) {
    int r = ei[i], c = ei[(size_t)E + i];
    int pos = atomicAdd(&cnt[r], 1);
    rc[pos] = r | (c << 16);
    const f4v* b4 = reinterpret_cast<const f4v*>(bond + (size_t)i * 16);
    i32x4 o;
    o[0] = (int)enc_fp8x4(b4[0]);
    o[1] = (int)enc_fp8x4(b4[1]);
    o[2] = (int)enc_fp8x4(b4[2]);
    o[3] = (int)enc_fp8x4(b4[3]);
    *reinterpret_cast<i32x4*>(bond8 + (size_t)pos * 4) = o;
  }
}

// ---------- fused edge kernel v14 (r14 verified, FROZEN) ----------
__global__ __launch_bounds__(512, 4) void edge_mlp14(
    const short* __restrict__ Gs, const int* __restrict__ rc,
    const unsigned* __restrict__ bond8, const short* __restrict__ wp,
    const float* __restrict__ b1, const float* __restrict__ b2,
    float* __restrict__ out, int E) {
  __shared__ __align__(16) char ubuf[8 * 16 * 136 * 2];   // Plds/Sred union, wave-private
  __shared__ __align__(16) short wlds[20480];             // 40 chunks x 512 shorts
  short (*Plds)[16][136] = reinterpret_cast<short(*)[16][136]>(ubuf);
  float (*Sred)[16][68]  = reinterpret_cast<float(*)[16][68]>(ubuf);

  const int tid = threadIdx.x;
  const int w = tid >> 6, l = tid & 63;
  const int q = l >> 4, c = l & 15;

  // stage weights (one contiguous 40KB copy), single barrier
  {
    const s16x8* src = reinterpret_cast<const s16x8*>(wp + 32768);
    s16x8* dst = reinterpret_cast<s16x8*>(wlds);
#pragma unroll
    for (int i = 0; i < 5; ++i) dst[tid + i * 512] = src[tid + i * 512];
  }
  __syncthreads();
  const short* wl1 = wlds;            // W1c: nt*512
  const short* wl2 = wlds + 4096;     // W2:  (kk*8+nt)*512

  // XCD-chunked bijective swizzle
  int nwg = gridDim.x;
  int qq = nwg >> 3, rr = nwg & 7;
  int xcd = blockIdx.x & 7, idx = blockIdx.x >> 3;
  int sbid = (xcd < rr ? xcd * (qq + 1) : rr * (qq + 1) + (xcd - rr) * qq) + idx;
  const int eb = sbid * 128;
  const int we = w * 16;

  // per-wave edge metadata
  int rcv = 0xFFFF;
  if (l < 16) {
    int gpos = eb + we + l;
    if (gpos < E) rcv = rc[gpos];
  }
  int v = __shfl(rcv, c);
  int rv = v & 0xffff;
  int rA = (rv == 0xFFFF) ? 0 : rv;
  int cA = ((unsigned)v) >> 16;

  int vn = __shfl(rcv, (l + 1) & 63);
  unsigned long long bm = __ballot(
      (l < 16) && ((rcv & 0xffff) != ((l < 15) ? (vn & 0xffff) : -1)));

  // hoisted gathers
  s16x8 g1v[4];
  i32x4 g2v[2];
  s16x8 az = {};
  {
    const short* gb = Gs + (size_t)rA * 192;
#pragma unroll
    for (int kk = 0; kk < 4; ++kk)
      g1v[kk] = *reinterpret_cast<const s16x8*>(gb + kk * 32 + q * 8);
    const char* g2b = (const char*)Gs + (size_t)cA * 384 + 256 + q * 32;
    g2v[0] = *reinterpret_cast<const i32x4*>(g2b);
    g2v[1] = *reinterpret_cast<const i32x4*>(g2b + 16);
    if (q < 2) {
      int ge = eb + we + c; if (ge >= E) ge = E - 1;
      uint2 d = *reinterpret_cast<const uint2*>(bond8 + (size_t)ge * 4 + q * 2);
      float f[8];
      dec_fp8x4(d.x, f);
      dec_fp8x4(d.y, f + 4);
      i32x4 aw;
#pragma unroll
      for (int p = 0; p < 4; ++p)
        aw[p] = (int)cvtpk_bf16(f[2 * p], f[2 * p + 1]);
      az = __builtin_bit_cast(s16x8, aw);
    }
  }

  // phase 1: bond @ W1c
  f32x4 acc[8];
#pragma unroll
  for (int nt = 0; nt < 8; ++nt) acc[nt] = (f32x4){0.f, 0.f, 0.f, 0.f};
  __builtin_amdgcn_s_setprio(1);
#pragma unroll
  for (int nt = 0; nt < 8; ++nt) {
    s16x8 b = *reinterpret_cast<const s16x8*>(wl1 + nt * 512 + l * 8);
    acc[nt] = MFMA_BF16(az, b, acc[nt], 0, 0, 0);
  }
  __builtin_amdgcn_s_setprio(0);

  // bridge C->A through LDS, fold b1
#pragma unroll
  for (int nt = 0; nt < 8; ++nt) {
    float bias = b1[nt * 16 + c];
    unsigned p01 = cvtpk_bf16(acc[nt][0] + bias, acc[nt][1] + bias);
    unsigned p23 = cvtpk_bf16(acc[nt][2] + bias, acc[nt][3] + bias);
    Plds[w][q * 4 + 0][nt * 16 + c] = (short)(p01 & 0xffffu);
    Plds[w][q * 4 + 1][nt * 16 + c] = (short)(p01 >> 16);
    Plds[w][q * 4 + 2][nt * 16 + c] = (short)(p23 & 0xffffu);
    Plds[w][q * 4 + 3][nt * 16 + c] = (short)(p23 >> 16);
  }

  // phase 2: GEMM2
#pragma unroll
  for (int nt = 0; nt < 8; ++nt) acc[nt] = (f32x4){0.f, 0.f, 0.f, 0.f};

#pragma unroll
  for (int kk = 0; kk < 4; ++kk) {
    s16x8 gk = g1v[kk];
    unsigned d0 = (unsigned)g2v[kk >> 1][(kk & 1) * 2 + 0];
    unsigned d1 = (unsigned)g2v[kk >> 1][(kk & 1) * 2 + 1];
    float g2f[8];
    dec_fp8x4(d0, g2f);
    dec_fp8x4(d1, g2f + 4);
    s16x8 pb = *reinterpret_cast<const s16x8*>(&Plds[w][c][kk * 32 + q * 8]);
    float sv[8];
#pragma unroll
    for (int j = 0; j < 8; ++j) {
      float x = bf2f(gk[j]) + g2f[j] + bf2f(pb[j]);
      float e = __expf(-x);
      sv[j] = x * __builtin_amdgcn_rcpf(1.f + e);
    }
    i32x4 a2w;
#pragma unroll
    for (int p = 0; p < 4; ++p)
      a2w[p] = (int)cvtpk_bf16(sv[2 * p], sv[2 * p + 1]);
    s16x8 a2 = __builtin_bit_cast(s16x8, a2w);
    __builtin_amdgcn_s_setprio(1);
#pragma unroll
    for (int nt = 0; nt < 8; ++nt) {
      s16x8 b = *reinterpret_cast<const s16x8*>(wl2 + (kk * 8 + nt) * 512 + l * 8);
      acc[nt] = MFMA_BF16(a2, b, acc[nt], 0, 0, 0);
    }
    __builtin_amdgcn_s_setprio(0);
  }

  // epilogue
#pragma unroll
  for (int h2 = 0; h2 < 2; ++h2) {
#pragma unroll
    for (int nt2 = 0; nt2 < 4; ++nt2) {
      int nt = h2 * 4 + nt2;
      float bias = b2[nt * 16 + c];
#pragma unroll
      for (int r = 0; r < 4; ++r)
        Sred[w][q * 4 + r][nt2 * 16 + c] = acc[nt][r] + bias;
    }
    float vsum = 0.f;
#pragma unroll
    for (int r = 0; r < 16; ++r) {
      vsum += Sred[w][r][l];
      if ((bm >> r) & 1ull) {
        int rowv = __shfl(rcv, r) & 0xffff;
        if (rowv != 0xFFFF)
          unsafeAtomicAdd(&out[(size_t)rowv * 128 + h2 * 64 + l], vsum);
        vsum = 0.f;
      }
    }
  }
}

// ---------- ultimate fallback (round-1 verified, wp-only) ----------
__global__ __launch_bounds__(256, 2) void edge_mlp(
    const float* __restrict__ h, const int* __restrict__ ei,
    const float* __restrict__ bond, const short* __restrict__ wp,
    const float* __restrict__ b1, const float* __restrict__ b2,
    float* __restrict__ out, int E) {
  __shared__ __align__(16) short Plds[4][64][136];
  __shared__ int rows_s[256];
  __shared__ int cols_s[256];
  const int tid = threadIdx.x;
  const int w = tid >> 6, l = tid & 63;
  const int q = l >> 4, c = l & 15;
  const int eb = blockIdx.x * 256;
  {
    int e = eb + tid; if (e >= E) e = E - 1;
    rows_s[tid] = ei[e];
    cols_s[tid] = ei[(size_t)E + e];
  }
  __syncthreads();
  const int we = w * 64;
  int rN[4], cN[4], eI[4];
#pragma unroll
  for (int mi = 0; mi < 4; ++mi) {
    int el = we + mi * 16 + c;
    rN[mi] = rows_s[el]; cN[mi] = cols_s[el];
    int eg = eb + el; if (eg >= E) eg = E - 1;
    eI[mi] = eg;
  }
  f32x4 acc[4][8];
#pragma unroll
  for (int mi = 0; mi < 4; ++mi)
#pragma unroll
    for (int nt = 0; nt < 8; ++nt) acc[mi][nt] = (f32x4){0.f, 0.f, 0.f, 0.f};
#pragma unroll
  for (int part = 0; part < 2; ++part) {
#pragma unroll
    for (int kk = 0; kk < 4; ++kk) {
      s16x8 a[4];
#pragma unroll
      for (int mi = 0; mi < 4; ++mi) {
        int node = part ? cN[mi] : rN[mi];
        const float* src = h + (size_t)node * 128 + kk * 32 + q * 8;
        a[mi] = cvt8(*reinterpret_cast<const f4v*>(src),
                     *reinterpret_cast<const f4v*>(src + 4));
      }
      const int kkg = part * 4 + kk;
#pragma unroll
      for (int nt = 0; nt < 8; ++nt) {
        s16x8 b = *reinterpret_cast<const s16x8*>(wp + (size_t)(kkg * 8 + nt) * 512 + l * 8);
#pragma unroll
        for (int mi = 0; mi < 4; ++mi)
          acc[mi][nt] = MFMA_BF16(a[mi], b, acc[mi][nt], 0, 0, 0);
      }
    }
  }
  {
    s16x8 a[4];
#pragma unroll
    for (int mi = 0; mi < 4; ++mi) {
      s16x8 az = {};
      if (q < 2) {
        const float* src = bond + (size_t)eI[mi] * 16 + q * 8;
        az = cvt8(*reinterpret_cast<const f4v*>(src),
                  *reinterpret_cast<const f4v*>(src + 4));
      }
      a[mi] = az;
    }
#pragma unroll
    for (int nt = 0; nt < 8; ++nt) {
      s16x8 b = *reinterpret_cast<const s16x8*>(wp + (size_t)(64 + nt) * 512 + l * 8);
#pragma unroll
      for (int mi = 0; mi < 4; ++mi)
        acc[mi][nt] = MFMA_BF16(a[mi], b, acc[mi][nt], 0, 0, 0);
    }
  }
#pragma unroll
  for (int nt = 0; nt < 8; ++nt) {
    float bias = b1[nt * 16 + c];
#pragma unroll
    for (int mi = 0; mi < 4; ++mi)
#pragma unroll
      for (int r = 0; r < 4; ++r) {
        float x = acc[mi][nt][r] + bias;
        float s = x / (1.f + __expf(-x));
        Plds[w][mi * 16 + q * 4 + r][nt * 16 + c] = f2bf(s);
      }
  }
  f32x4 acc2[4][8];
#pragma unroll
  for (int mi = 0; mi < 4; ++mi)
#pragma unroll
    for (int nt = 0; nt < 8; ++nt) acc2[mi][nt] = (f32x4){0.f, 0.f, 0.f, 0.f};
#pragma unroll
  for (int kk = 0; kk < 4; ++kk) {
    s16x8 a2[4];
#pragma unroll
    for (int mi = 0; mi < 4; ++mi)
      a2[mi] = *reinterpret_cast<const s16x8*>(&Plds[w][mi * 16 + c][kk * 32 + q * 8]);
#pragma unroll
    for (int nt = 0; nt < 8; ++nt) {
      s16x8 b = *reinterpret_cast<const s16x8*>(wp + 36864 + (size_t)(kk * 8 + nt) * 512 + l * 8);
#pragma unroll
      for (int mi = 0; mi < 4; ++mi)
        acc2[mi][nt] = MFMA_BF16(a2[mi], b, acc2[mi][nt], 0, 0, 0);
    }
  }
#pragma unroll
  for (int nt = 0; nt < 8; ++nt) {
    float bias = b2[nt * 16 + c];
#pragma unroll
    for (int mi = 0; mi < 4; ++mi)
#pragma unroll
      for (int r = 0; r < 4; ++r) {
        int el = we + mi * 16 + q * 4 + r;
        if ((eb + el) < E) {
          int node = rows_s[el];
          unsafeAtomicAdd(&out[(size_t)node * 128 + nt * 16 + c],
                          acc2[mi][nt][r] + bias);
        }
      }
  }
}

extern "C" void kernel_launch(void* const* d_in, const int* in_sizes, int n_in,
                              void* d_out, int out_size, void* d_ws, size_t ws_size,
                              hipStream_t stream) {
  const float* h    = (const float*)d_in[0];
  const int*   ei   = (const int*)d_in[1];
  const float* bond = (const float*)d_in[2];
  const float* W1   = (const float*)d_in[3];
  const float* b1   = (const float*)d_in[4];
  const float* W2   = (const float*)d_in[5];
  const float* b2   = (const float*)d_in[6];
  float* out = (float*)d_out;
  char* ws = (char*)d_ws;

  const int E  = in_sizes[1] / 2;
  const int NN = in_sizes[0] / 128;

  // ws layout (bytes, 16-aligned)
  short* wp = (short*)ws;                                   // 131072
  size_t off_G    = 131072;
  size_t off_cnt  = off_G + (size_t)NN * 384;
  size_t off_par  = off_cnt + (((size_t)NN * 4 + 15) & ~15ull);
  size_t off_idx  = off_par + 4096;
  size_t off_bs   = off_idx + (((size_t)E * 4 + 15) & ~15ull);
  size_t need15   = off_bs + (size_t)E * 16;                // fp8 sorted bond

  if (ws_size >= need15 && NN <= 65535) {
    short*    Gs    = (short*)(ws + off_G);
    int*      cnt   = (int*)(ws + off_cnt);
    int*      par   = (int*)(ws + off_par);
    int*      rc    = (int*)(ws + off_idx);
    unsigned* bond8 = (unsigned*)(ws + off_bs);
    const int NB_G = (NN + 63) / 64;
    int outN4 = NN * 32;
    int E_ = E, NN_ = NN;

    // prep: weights + cnt zero (out zeroed inside k_sss)
    prep_weights<<<64, 256, 0, stream>>>(W1, W2, wp, (float*)nullptr, 0, cnt, NN);
    k_gh<<<NB_G + NB_H, 256, 0, stream>>>(h, wp, Gs, ei, cnt, NN, NB_G, E);

    void* args[] = {(void*)&ei, (void*)&cnt, (void*)&par, (void*)&rc,
                    (void*)&bond8, (void*)&bond, (void*)&out,
                    (void*)&E_, (void*)&NN_, (void*)&outN4};
    hipError_t ce = hipLaunchCooperativeKernel((const void*)k_sss,
                                               dim3(1024), dim3(256),
                                               args, 0, stream);
    if (ce != hipSuccess) {
      // fallback: verified r14 path (out zero + 3-kernel scan/scatter)
      hipMemsetAsync(out, 0, (size_t)NN * 128 * sizeof(float), stream);
      const int P = (NN + 1023) / 1024;
      k_s1<<<P, 1024, 0, stream>>>(cnt, par, NN);
      k_s3m<<<P, 1024, 0, stream>>>(cnt, par, NN);
      k_scatter13<<<2048, 256, 0, stream>>>(ei, cnt, rc, bond8, bond, E);
    }
    edge_mlp14<<<(E + 127) / 128, 512, 0, stream>>>(Gs, rc, bond8, wp, b1, b2, out, E);
  } else {
    hipMemsetAsync(d_out, 0, (size_t)NN * 128 * sizeof(float), stream);
    prep_weights<<<64, 256, 0, stream>>>(W1, W2, wp, (float*)nullptr, 0,
                                         (int*)nullptr, 0);
    edge_mlp<<<(E + 255) / 256, 256, 0, stream>>>(h, ei, bond, wp, b1, b2, out, E);
  }
}

// Round 16
// 510.294 us; speedup vs baseline: 1.1982x; 1.1982x over previous
//
#include <hip/hip_runtime.h>

typedef __attribute__((ext_vector_type(4))) float  f32x4;
typedef __attribute__((ext_vector_type(2))) float  f32x2;
typedef __attribute__((ext_vector_type(8))) short  s16x8;
typedef __attribute__((ext_vector_type(4))) float  f4v;
typedef __attribute__((ext_vector_type(4))) int    i32x4;

#define MFMA_BF16 __builtin_amdgcn_mfma_f32_16x16x32_bf16
#define SENT 0x7fffffff

#if defined(__has_builtin)
#if __has_builtin(__builtin_amdgcn_cvt_pk_fp8_f32) && __has_builtin(__builtin_amdgcn_cvt_pk_f32_fp8)
#define HW8 1
#endif
#endif

// ---------- helpers ----------
__device__ __forceinline__ short f2bf(float f) {
  unsigned u = __builtin_bit_cast(unsigned, f);
  u += 0x7fffu + ((u >> 16) & 1u);
  return (short)(u >> 16);
}
__device__ __forceinline__ float bf2f(short s) {
  unsigned u = ((unsigned)(unsigned short)s) << 16;
  return __builtin_bit_cast(float, u);
}
__device__ __forceinline__ s16x8 cvt8(f4v f0, f4v f1) {
  s16x8 r;
  r[0] = f2bf(f0[0]); r[1] = f2bf(f0[1]); r[2] = f2bf(f0[2]); r[3] = f2bf(f0[3]);
  r[4] = f2bf(f1[0]); r[5] = f2bf(f1[1]); r[6] = f2bf(f1[2]); r[7] = f2bf(f1[3]);
  return r;
}
// HW packed bf16 convert (gfx950)
__device__ __forceinline__ unsigned cvtpk_bf16(float a, float b) {
  unsigned r;
  asm("v_cvt_pk_bf16_f32 %0, %1, %2" : "=v"(r) : "v"(a), "v"(b));
  return r;
}
// manual fp8 e4m3fn (fallback when no HW builtin)
__device__ __forceinline__ unsigned f2fp8(float x) {
  unsigned u = __builtin_bit_cast(unsigned, x);
  unsigned s = (u >> 24) & 0x80u;
  unsigned au = u & 0x7fffffffu;
  if (au < 0x3C800000u) return s;
  unsigned biased = au - 0x3C000000u;
  unsigned val = biased >> 20;
  unsigned rem = biased & 0xFFFFFu;
  val += (rem > 0x80000u) || (rem == 0x80000u && (val & 1u));
  if (val > 0x7Eu) val = 0x7Eu;
  return s | val;
}
__device__ __forceinline__ float fp8tof(unsigned b) {
  unsigned em = b & 0x7fu;
  unsigned f = ((em + 960u) << 20) | ((b & 0x80u) << 24);
  return (em < 8u) ? 0.f : __builtin_bit_cast(float, f);
}
__device__ __forceinline__ unsigned char enc_fp8(float x) {
#ifdef HW8
  return (unsigned char)(__builtin_amdgcn_cvt_pk_fp8_f32(x, x, 0u, false) & 0xffu);
#else
  return (unsigned char)f2fp8(x);
#endif
}
// pack 4 floats -> 4 fp8 bytes in one dword
__device__ __forceinline__ unsigned enc_fp8x4(f4v v) {
#ifdef HW8
  unsigned u = __builtin_amdgcn_cvt_pk_fp8_f32(v[0], v[1], 0u, false);
  u = __builtin_amdgcn_cvt_pk_fp8_f32(v[2], v[3], u, true);
  return u;
#else
  return f2fp8(v[0]) | (f2fp8(v[1]) << 8) | (f2fp8(v[2]) << 16) | (f2fp8(v[3]) << 24);
#endif
}
__device__ __forceinline__ void dec_fp8x4(unsigned d, float* f) {
#ifdef HW8
  f32x2 lo = __builtin_amdgcn_cvt_pk_f32_fp8(d, false);
  f32x2 hi = __builtin_amdgcn_cvt_pk_f32_fp8(d, true);
  f[0] = lo[0]; f[1] = lo[1]; f[2] = hi[0]; f[3] = hi[1];
#else
#pragma unroll
  for (int j = 0; j < 4; ++j) f[j] = fp8tof((d >> (8 * j)) & 0xffu);
#endif
}

// ---------- weight prep + fused zeroing of out & cnt (r12/r14 verified) ----------
__global__ __launch_bounds__(256) void prep_weights(
    const float* __restrict__ W1, const float* __restrict__ W2,
    short* __restrict__ wp, float* __restrict__ out, int outN4,
    int* __restrict__ cnt, int NN) {
  int t = blockIdx.x * 256 + threadIdx.x;
  int total = gridDim.x * 256;
  if (out) {
    f32x4* o4 = reinterpret_cast<f32x4*>(out);
    for (int i = t; i < outN4; i += total) o4[i] = (f32x4){0.f, 0.f, 0.f, 0.f};
  }
  if (cnt) {
    for (int i = t; i < NN; i += total) cnt[i] = 0;
  }
  int chunk = t >> 6, l = t & 63;
  if (chunk >= 104) return;
  int q = l >> 4, c = l & 15;
  s16x8 v;
  if (chunk < 72) {
    int kk = chunk >> 3, nt = chunk & 7;
    int k0 = kk * 32 + q * 8, n = nt * 16 + c;
#pragma unroll
    for (int j = 0; j < 8; ++j) {
      int k = k0 + j;
      v[j] = (k < 272) ? f2bf(W1[k * 128 + n]) : (short)0;
    }
    *reinterpret_cast<s16x8*>(wp + (size_t)chunk * 512 + l * 8) = v;
  } else {
    int c2 = chunk - 72;
    int kk = c2 >> 3, nt = c2 & 7;
    int k0 = kk * 32 + q * 8, n = nt * 16 + c;
#pragma unroll
    for (int j = 0; j < 8; ++j) v[j] = f2bf(W2[(k0 + j) * 128 + n]);
    *reinterpret_cast<s16x8*>(wp + 36864 + (size_t)c2 * 512 + l * 8) = v;
  }
}

// ---------- fused dense G + edge histogram (r4 verified) ----------
// G layout per node: 384 B = [128 bf16 G1 (row half)] [128 B fp8 G2 (col half, permuted)]
#define NB_H 512
__global__ __launch_bounds__(256) void k_gh(
    const float* __restrict__ h, const short* __restrict__ wp,
    short* __restrict__ Gs, const int* __restrict__ ei,
    int* __restrict__ cnt, int NN, int NB_G, int E) {
  if ((int)blockIdx.x >= NB_G) {
    int i = ((int)blockIdx.x - NB_G) * 256 + threadIdx.x;
    for (; i < E; i += NB_H * 256) atomicAdd(&cnt[ei[i]], 1);
    return;
  }
  const int tid = threadIdx.x;
  const int w = tid >> 6, l = tid & 63;
  const int q = l >> 4, c = l & 15;
  const int nb = blockIdx.x * 64 + w * 16;

  f32x4 acc[16];
#pragma unroll
  for (int nt = 0; nt < 16; ++nt) acc[nt] = (f32x4){0.f, 0.f, 0.f, 0.f};

#pragma unroll
  for (int kk = 0; kk < 4; ++kk) {
    int node = nb + c; if (node >= NN) node = NN - 1;
    const float* src = h + (size_t)node * 128 + kk * 32 + q * 8;
    s16x8 a = cvt8(*reinterpret_cast<const f4v*>(src),
                   *reinterpret_cast<const f4v*>(src + 4));
#pragma unroll
    for (int nt2 = 0; nt2 < 16; ++nt2) {
      int kkg = kk + ((nt2 >= 8) ? 4 : 0);
      int chunk = kkg * 8 + (nt2 & 7);
      s16x8 b = *reinterpret_cast<const s16x8*>(wp + (size_t)chunk * 512 + l * 8);
      acc[nt2] = MFMA_BF16(a, b, acc[nt2], 0, 0, 0);
    }
  }
  unsigned char* Gb = (unsigned char*)Gs;
#pragma unroll
  for (int nt2 = 0; nt2 < 16; ++nt2)
#pragma unroll
    for (int r = 0; r < 4; ++r) {
      int node = nb + q * 4 + r;
      if (node < NN) {
        if (nt2 < 8) {
          Gs[(size_t)node * 192 + nt2 * 16 + c] = f2bf(acc[nt2][r]);
        } else {
          int n7 = nt2 - 8;
          int addr = ((n7 & 1) * 2 + (c >> 3)) * 32 + (n7 >> 1) * 8 + (c & 7);
          Gb[(size_t)node * 384 + 256 + addr] = enc_fp8(acc[nt2][r]);
        }
      }
    }
}

// ---------- 2-phase scan (r13/r14 verified) ----------
__global__ __launch_bounds__(1024) void k_s1(const int* __restrict__ cnt,
                                             int* __restrict__ partial, int NN) {
  __shared__ int red[16];
  int t = threadIdx.x, idx = blockIdx.x * 1024 + t;
  int v = (idx < NN) ? cnt[idx] : 0;
#pragma unroll
  for (int d = 1; d < 64; d <<= 1) v += __shfl_xor(v, d);
  if ((t & 63) == 0) red[t >> 6] = v;
  __syncthreads();
  if (t == 0) {
    int s = 0;
#pragma unroll
    for (int i = 0; i < 16; ++i) s += red[i];
    partial[blockIdx.x] = s;
  }
}
__global__ __launch_bounds__(1024) void k_s3m(int* __restrict__ cnt,
                                              const int* __restrict__ partial,
                                              int NN) {
  __shared__ int ps[1024];
  __shared__ int pbuf[64];
  __shared__ int base_s;
  int t = threadIdx.x, bid = blockIdx.x, idx = bid * 1024 + t;
  if (t < 64) pbuf[t] = (t < bid) ? partial[t] : 0;   // P <= 64 (NN <= 65536)
  int v = (idx < NN) ? cnt[idx] : 0;
  ps[t] = v;
  __syncthreads();
  if (t == 0) {
    int b = 0;
#pragma unroll
    for (int j = 0; j < 64; ++j) b += pbuf[j];
    base_s = b;
  }
  for (int d = 1; d < 1024; d <<= 1) {
    int u = (t >= d) ? ps[t - d] : 0;
    __syncthreads(); ps[t] += u; __syncthreads();
  }
  if (idx < NN) cnt[idx] = ps[t] - v + base_s;
}

// ---------- two-phase scatter (r16): kill random-wide-store amplification ----------
// Phase A: only random store is ONE 4B word per edge (perm).
__global__ void k_scatterA(const int* __restrict__ ei, int* __restrict__ cnt,
                           int* __restrict__ perm, int E) {
  int i = blockIdx.x * blockDim.x + threadIdx.x;
  int stride = gridDim.x * blockDim.x;
  for (; i < E; i += stride) {
    int r = ei[i];
    int pos = atomicAdd(&cnt[r], 1);
    perm[pos] = i;
  }
}
// Phase B: sequential perm read -> sequential rc/bond8 writes; random READS only
// (ei 12.8MB L2/L3-resident 4B x2; bond 102MB L3-resident, 64B-line aligned).
__global__ void k_scatterB(const int* __restrict__ ei,
                           const int* __restrict__ perm,
                           int* __restrict__ rc, unsigned* __restrict__ bond8,
                           const float* __restrict__ bond, int E) {
  int p = blockIdx.x * blockDim.x + threadIdx.x;
  int stride = gridDim.x * blockDim.x;
  for (; p < E; p += stride) {
    int e = perm[p];
    int r = ei[e], c = ei[(size_t)E + e];
    rc[p] = r | (c << 16);
    const f4v* b4 = reinterpret_cast<const f4v*>(bond + (size_t)e * 16);
    i32x4 o;
    o[0] = (int)enc_fp8x4(b4[0]);
    o[1] = (int)enc_fp8x4(b4[1]);
    o[2] = (int)enc_fp8x4(b4[2]);
    o[3] = (int)enc_fp8x4(b4[3]);
    *reinterpret_cast<i32x4*>(bond8 + (size_t)p * 4) = o;
  }
}

// ---------- fused edge kernel v14 (r14 verified, FROZEN) ----------
__global__ __launch_bounds__(512, 4) void edge_mlp14(
    const short* __restrict__ Gs, const int* __restrict__ rc,
    const unsigned* __restrict__ bond8, const short* __restrict__ wp,
    const float* __restrict__ b1, const float* __restrict__ b2,
    float* __restrict__ out, int E) {
  __shared__ __align__(16) char ubuf[8 * 16 * 136 * 2];   // Plds/Sred union, wave-private
  __shared__ __align__(16) short wlds[20480];             // 40 chunks x 512 shorts
  short (*Plds)[16][136] = reinterpret_cast<short(*)[16][136]>(ubuf);
  float (*Sred)[16][68]  = reinterpret_cast<float(*)[16][68]>(ubuf);

  const int tid = threadIdx.x;
  const int w = tid >> 6, l = tid & 63;
  const int q = l >> 4, c = l & 15;

  // stage weights (one contiguous 40KB copy), single barrier
  {
    const s16x8* src = reinterpret_cast<const s16x8*>(wp + 32768);
    s16x8* dst = reinterpret_cast<s16x8*>(wlds);
#pragma unroll
    for (int i = 0; i < 5; ++i) dst[tid + i * 512] = src[tid + i * 512];
  }
  __syncthreads();
  const short* wl1 = wlds;            // W1c: nt*512
  const short* wl2 = wlds + 4096;     // W2:  (kk*8+nt)*512

  // XCD-chunked bijective swizzle
  int nwg = gridDim.x;
  int qq = nwg >> 3, rr = nwg & 7;
  int xcd = blockIdx.x & 7, idx = blockIdx.x >> 3;
  int sbid = (xcd < rr ? xcd * (qq + 1) : rr * (qq + 1) + (xcd - rr) * qq) + idx;
  const int eb = sbid * 128;
  const int we = w * 16;

  // per-wave edge metadata
  int rcv = 0xFFFF;
  if (l < 16) {
    int gpos = eb + we + l;
    if (gpos < E) rcv = rc[gpos];
  }
  int v = __shfl(rcv, c);
  int rv = v & 0xffff;
  int rA = (rv == 0xFFFF) ? 0 : rv;
  int cA = ((unsigned)v) >> 16;

  int vn = __shfl(rcv, (l + 1) & 63);
  unsigned long long bm = __ballot(
      (l < 16) && ((rcv & 0xffff) != ((l < 15) ? (vn & 0xffff) : -1)));

  // hoisted gathers
  s16x8 g1v[4];
  i32x4 g2v[2];
  s16x8 az = {};
  {
    const short* gb = Gs + (size_t)rA * 192;
#pragma unroll
    for (int kk = 0; kk < 4; ++kk)
      g1v[kk] = *reinterpret_cast<const s16x8*>(gb + kk * 32 + q * 8);
    const char* g2b = (const char*)Gs + (size_t)cA * 384 + 256 + q * 32;
    g2v[0] = *reinterpret_cast<const i32x4*>(g2b);
    g2v[1] = *reinterpret_cast<const i32x4*>(g2b + 16);
    if (q < 2) {
      int ge = eb + we + c; if (ge >= E) ge = E - 1;
      uint2 d = *reinterpret_cast<const uint2*>(bond8 + (size_t)ge * 4 + q * 2);
      float f[8];
      dec_fp8x4(d.x, f);
      dec_fp8x4(d.y, f + 4);
      i32x4 aw;
#pragma unroll
      for (int p = 0; p < 4; ++p)
        aw[p] = (int)cvtpk_bf16(f[2 * p], f[2 * p + 1]);
      az = __builtin_bit_cast(s16x8, aw);
    }
  }

  // phase 1: bond @ W1c
  f32x4 acc[8];
#pragma unroll
  for (int nt = 0; nt < 8; ++nt) acc[nt] = (f32x4){0.f, 0.f, 0.f, 0.f};
  __builtin_amdgcn_s_setprio(1);
#pragma unroll
  for (int nt = 0; nt < 8; ++nt) {
    s16x8 b = *reinterpret_cast<const s16x8*>(wl1 + nt * 512 + l * 8);
    acc[nt] = MFMA_BF16(az, b, acc[nt], 0, 0, 0);
  }
  __builtin_amdgcn_s_setprio(0);

  // bridge C->A through LDS, fold b1
#pragma unroll
  for (int nt = 0; nt < 8; ++nt) {
    float bias = b1[nt * 16 + c];
    unsigned p01 = cvtpk_bf16(acc[nt][0] + bias, acc[nt][1] + bias);
    unsigned p23 = cvtpk_bf16(acc[nt][2] + bias, acc[nt][3] + bias);
    Plds[w][q * 4 + 0][nt * 16 + c] = (short)(p01 & 0xffffu);
    Plds[w][q * 4 + 1][nt * 16 + c] = (short)(p01 >> 16);
    Plds[w][q * 4 + 2][nt * 16 + c] = (short)(p23 & 0xffffu);
    Plds[w][q * 4 + 3][nt * 16 + c] = (short)(p23 >> 16);
  }

  // phase 2: GEMM2
#pragma unroll
  for (int nt = 0; nt < 8; ++nt) acc[nt] = (f32x4){0.f, 0.f, 0.f, 0.f};

#pragma unroll
  for (int kk = 0; kk < 4; ++kk) {
    s16x8 gk = g1v[kk];
    unsigned d0 = (unsigned)g2v[kk >> 1][(kk & 1) * 2 + 0];
    unsigned d1 = (unsigned)g2v[kk >> 1][(kk & 1) * 2 + 1];
    float g2f[8];
    dec_fp8x4(d0, g2f);
    dec_fp8x4(d1, g2f + 4);
    s16x8 pb = *reinterpret_cast<const s16x8*>(&Plds[w][c][kk * 32 + q * 8]);
    float sv[8];
#pragma unroll
    for (int j = 0; j < 8; ++j) {
      float x = bf2f(gk[j]) + g2f[j] + bf2f(pb[j]);
      float e = __expf(-x);
      sv[j] = x * __builtin_amdgcn_rcpf(1.f + e);
    }
    i32x4 a2w;
#pragma unroll
    for (int p = 0; p < 4; ++p)
      a2w[p] = (int)cvtpk_bf16(sv[2 * p], sv[2 * p + 1]);
    s16x8 a2 = __builtin_bit_cast(s16x8, a2w);
    __builtin_amdgcn_s_setprio(1);
#pragma unroll
    for (int nt = 0; nt < 8; ++nt) {
      s16x8 b = *reinterpret_cast<const s16x8*>(wl2 + (kk * 8 + nt) * 512 + l * 8);
      acc[nt] = MFMA_BF16(a2, b, acc[nt], 0, 0, 0);
    }
    __builtin_amdgcn_s_setprio(0);
  }

  // epilogue
#pragma unroll
  for (int h2 = 0; h2 < 2; ++h2) {
#pragma unroll
    for (int nt2 = 0; nt2 < 4; ++nt2) {
      int nt = h2 * 4 + nt2;
      float bias = b2[nt * 16 + c];
#pragma unroll
      for (int r = 0; r < 4; ++r)
        Sred[w][q * 4 + r][nt2 * 16 + c] = acc[nt][r] + bias;
    }
    float vsum = 0.f;
#pragma unroll
    for (int r = 0; r < 16; ++r) {
      vsum += Sred[w][r][l];
      if ((bm >> r) & 1ull) {
        int rowv = __shfl(rcv, r) & 0xffff;
        if (rowv != 0xFFFF)
          unsafeAtomicAdd(&out[(size_t)rowv * 128 + h2 * 64 + l], vsum);
        vsum = 0.f;
      }
    }
  }
}

// ---------- ultimate fallback (round-1 verified, wp-only) ----------
__global__ __launch_bounds__(256, 2) void edge_mlp(
    const float* __restrict__ h, const int* __restrict__ ei,
    const float* __restrict__ bond, const short* __restrict__ wp,
    const float* __restrict__ b1, const float* __restrict__ b2,
    float* __restrict__ out, int E) {
  __shared__ __align__(16) short Plds[4][64][136];
  __shared__ int rows_s[256];
  __shared__ int cols_s[256];
  const int tid = threadIdx.x;
  const int w = tid >> 6, l = tid & 63;
  const int q = l >> 4, c = l & 15;
  const int eb = blockIdx.x * 256;
  {
    int e = eb + tid; if (e >= E) e = E - 1;
    rows_s[tid] = ei[e];
    cols_s[tid] = ei[(size_t)E + e];
  }
  __syncthreads();
  const int we = w * 64;
  int rN[4], cN[4], eI[4];
#pragma unroll
  for (int mi = 0; mi < 4; ++mi) {
    int el = we + mi * 16 + c;
    rN[mi] = rows_s[el]; cN[mi] = cols_s[el];
    int eg = eb + el; if (eg >= E) eg = E - 1;
    eI[mi] = eg;
  }
  f32x4 acc[4][8];
#pragma unroll
  for (int mi = 0; mi < 4; ++mi)
#pragma unroll
    for (int nt = 0; nt < 8; ++nt) acc[mi][nt] = (f32x4){0.f, 0.f, 0.f, 0.f};
#pragma unroll
  for (int part = 0; part < 2; ++part) {
#pragma unroll
    for (int kk = 0; kk < 4; ++kk) {
      s16x8 a[4];
#pragma unroll
      for (int mi = 0; mi < 4; ++mi) {
        int node = part ? cN[mi] : rN[mi];
        const float* src = h + (size_t)node * 128 + kk * 32 + q * 8;
        a[mi] = cvt8(*reinterpret_cast<const f4v*>(src),
                     *reinterpret_cast<const f4v*>(src + 4));
      }
      const int kkg = part * 4 + kk;
#pragma unroll
      for (int nt = 0; nt < 8; ++nt) {
        s16x8 b = *reinterpret_cast<const s16x8*>(wp + (size_t)(kkg * 8 + nt) * 512 + l * 8);
#pragma unroll
        for (int mi = 0; mi < 4; ++mi)
          acc[mi][nt] = MFMA_BF16(a[mi], b, acc[mi][nt], 0, 0, 0);
      }
    }
  }
  {
    s16x8 a[4];
#pragma unroll
    for (int mi = 0; mi < 4; ++mi) {
      s16x8 az = {};
      if (q < 2) {
        const float* src = bond + (size_t)eI[mi] * 16 + q * 8;
        az = cvt8(*reinterpret_cast<const f4v*>(src),
                  *reinterpret_cast<const f4v*>(src + 4));
      }
      a[mi] = az;
    }
#pragma unroll
    for (int nt = 0; nt < 8; ++nt) {
      s16x8 b = *reinterpret_cast<const s16x8*>(wp + (size_t)(64 + nt) * 512 + l * 8);
#pragma unroll
      for (int mi = 0; mi < 4; ++mi)
        acc[mi][nt] = MFMA_BF16(a[mi], b, acc[mi][nt], 0, 0, 0);
    }
  }
#pragma unroll
  for (int nt = 0; nt < 8; ++nt) {
    float bias = b1[nt * 16 + c];
#pragma unroll
    for (int mi = 0; mi < 4; ++mi)
#pragma unroll
      for (int r = 0; r < 4; ++r) {
        float x = acc[mi][nt][r] + bias;
        float s = x / (1.f + __expf(-x));
        Plds[w][mi * 16 + q * 4 + r][nt * 16 + c] = f2bf(s);
      }
  }
  f32x4 acc2[4][8];
#pragma unroll
  for (int mi = 0; mi < 4; ++mi)
#pragma unroll
    for (int nt = 0; nt < 8; ++nt) acc2[mi][nt] = (f32x4){0.f, 0.f, 0.f, 0.f};
#pragma unroll
  for (int kk = 0; kk < 4; ++kk) {
    s16x8 a2[4];
#pragma unroll
    for (int mi = 0; mi < 4; ++mi)
      a2[mi] = *reinterpret_cast<const s16x8*>(&Plds[w][mi * 16 + c][kk * 32 + q * 8]);
#pragma unroll
    for (int nt = 0; nt < 8; ++nt) {
      s16x8 b = *reinterpret_cast<const s16x8*>(wp + 36864 + (size_t)(kk * 8 + nt) * 512 + l * 8);
#pragma unroll
      for (int mi = 0; mi < 4; ++mi)
        acc2[mi][nt] = MFMA_BF16(a2[mi], b, acc2[mi][nt], 0, 0, 0);
    }
  }
#pragma unroll
  for (int nt = 0; nt < 8; ++nt) {
    float bias = b2[nt * 16 + c];
#pragma unroll
    for (int mi = 0; mi < 4; ++mi)
#pragma unroll
      for (int r = 0; r < 4; ++r) {
        int el = we + mi * 16 + q * 4 + r;
        if ((eb + el) < E) {
          int node = rows_s[el];
          unsafeAtomicAdd(&out[(size_t)node * 128 + nt * 16 + c],
                          acc2[mi][nt][r] + bias);
        }
      }
  }
}

extern "C" void kernel_launch(void* const* d_in, const int* in_sizes, int n_in,
                              void* d_out, int out_size, void* d_ws, size_t ws_size,
                              hipStream_t stream) {
  const float* h    = (const float*)d_in[0];
  const int*   ei   = (const int*)d_in[1];
  const float* bond = (const float*)d_in[2];
  const float* W1   = (const float*)d_in[3];
  const float* b1   = (const float*)d_in[4];
  const float* W2   = (const float*)d_in[5];
  const float* b2   = (const float*)d_in[6];
  float* out = (float*)d_out;
  char* ws = (char*)d_ws;

  const int E  = in_sizes[1] / 2;
  const int NN = in_sizes[0] / 128;

  // ws layout (bytes, 16-aligned)
  short* wp = (short*)ws;                                   // 131072
  size_t off_G    = 131072;
  size_t off_cnt  = off_G + (size_t)NN * 384;
  size_t off_par  = off_cnt + (((size_t)NN * 4 + 15) & ~15ull);
  size_t off_idx  = off_par + 4096;                         // rc: E*4
  size_t off_bs   = off_idx + (((size_t)E * 4 + 15) & ~15ull);
  size_t off_pm   = off_bs + (size_t)E * 16;                // perm: E*4
  size_t need16   = off_pm + (size_t)E * 4;

  if (ws_size >= need16 && NN <= 65535) {
    short*    Gs    = (short*)(ws + off_G);
    int*      cnt   = (int*)(ws + off_cnt);
    int*      par   = (int*)(ws + off_par);
    int*      rc    = (int*)(ws + off_idx);
    unsigned* bond8 = (unsigned*)(ws + off_bs);
    int*      perm  = (int*)(ws + off_pm);
    const int NB_G = (NN + 63) / 64;
    const int P    = (NN + 1023) / 1024;

    // prep_weights zeroes out (NN*32 f32x4) and cnt (r14-verified config)
    prep_weights<<<512, 256, 0, stream>>>(W1, W2, wp, out, NN * 32, cnt, NN);
    k_gh<<<NB_G + NB_H, 256, 0, stream>>>(h, wp, Gs, ei, cnt, NN, NB_G, E);
    k_s1<<<P, 1024, 0, stream>>>(cnt, par, NN);
    k_s3m<<<P, 1024, 0, stream>>>(cnt, par, NN);
    k_scatterA<<<2048, 256, 0, stream>>>(ei, cnt, perm, E);
    k_scatterB<<<2048, 256, 0, stream>>>(ei, perm, rc, bond8, bond, E);
    edge_mlp14<<<(E + 127) / 128, 512, 0, stream>>>(Gs, rc, bond8, wp, b1, b2, out, E);
  } else {
    hipMemsetAsync(d_out, 0, (size_t)NN * 128 * sizeof(float), stream);
    prep_weights<<<512, 256, 0, stream>>>(W1, W2, wp, (float*)nullptr, 0,
                                          (int*)nullptr, 0);
    edge_mlp<<<(E + 255) / 256, 256, 0, stream>>>(h, ei, bond, wp, b1, b2, out, E);
  }
}

// Round 17
// 384.827 us; speedup vs baseline: 1.5888x; 1.3260x over previous
//
#include <hip/hip_runtime.h>

typedef __attribute__((ext_vector_type(4))) float  f32x4;
typedef __attribute__((ext_vector_type(2))) float  f32x2;
typedef __attribute__((ext_vector_type(8))) short  s16x8;
typedef __attribute__((ext_vector_type(4))) float  f4v;
typedef __attribute__((ext_vector_type(4))) int    i32x4;

#define MFMA_BF16 __builtin_amdgcn_mfma_f32_16x16x32_bf16
#define SENT 0x7fffffff

#if defined(__has_builtin)
#if __has_builtin(__builtin_amdgcn_cvt_pk_fp8_f32) && __has_builtin(__builtin_amdgcn_cvt_pk_f32_fp8)
#define HW8 1
#endif
#endif

// ---------- helpers ----------
__device__ __forceinline__ short f2bf(float f) {
  unsigned u = __builtin_bit_cast(unsigned, f);
  u += 0x7fffu + ((u >> 16) & 1u);
  return (short)(u >> 16);
}
__device__ __forceinline__ float bf2f(short s) {
  unsigned u = ((unsigned)(unsigned short)s) << 16;
  return __builtin_bit_cast(float, u);
}
__device__ __forceinline__ s16x8 cvt8(f4v f0, f4v f1) {
  s16x8 r;
  r[0] = f2bf(f0[0]); r[1] = f2bf(f0[1]); r[2] = f2bf(f0[2]); r[3] = f2bf(f0[3]);
  r[4] = f2bf(f1[0]); r[5] = f2bf(f1[1]); r[6] = f2bf(f1[2]); r[7] = f2bf(f1[3]);
  return r;
}
// HW packed bf16 convert (gfx950)
__device__ __forceinline__ unsigned cvtpk_bf16(float a, float b) {
  unsigned r;
  asm("v_cvt_pk_bf16_f32 %0, %1, %2" : "=v"(r) : "v"(a), "v"(b));
  return r;
}
// manual fp8 e4m3fn (fallback when no HW builtin)
__device__ __forceinline__ unsigned f2fp8(float x) {
  unsigned u = __builtin_bit_cast(unsigned, x);
  unsigned s = (u >> 24) & 0x80u;
  unsigned au = u & 0x7fffffffu;
  if (au < 0x3C800000u) return s;
  unsigned biased = au - 0x3C000000u;
  unsigned val = biased >> 20;
  unsigned rem = biased & 0xFFFFFu;
  val += (rem > 0x80000u) || (rem == 0x80000u && (val & 1u));
  if (val > 0x7Eu) val = 0x7Eu;
  return s | val;
}
__device__ __forceinline__ float fp8tof(unsigned b) {
  unsigned em = b & 0x7fu;
  unsigned f = ((em + 960u) << 20) | ((b & 0x80u) << 24);
  return (em < 8u) ? 0.f : __builtin_bit_cast(float, f);
}
__device__ __forceinline__ unsigned char enc_fp8(float x) {
#ifdef HW8
  return (unsigned char)(__builtin_amdgcn_cvt_pk_fp8_f32(x, x, 0u, false) & 0xffu);
#else
  return (unsigned char)f2fp8(x);
#endif
}
// pack 4 floats -> 4 fp8 bytes in one dword
__device__ __forceinline__ unsigned enc_fp8x4(f4v v) {
#ifdef HW8
  unsigned u = __builtin_amdgcn_cvt_pk_fp8_f32(v[0], v[1], 0u, false);
  u = __builtin_amdgcn_cvt_pk_fp8_f32(v[2], v[3], u, true);
  return u;
#else
  return f2fp8(v[0]) | (f2fp8(v[1]) << 8) | (f2fp8(v[2]) << 16) | (f2fp8(v[3]) << 24);
#endif
}
__device__ __forceinline__ void dec_fp8x4(unsigned d, float* f) {
#ifdef HW8
  f32x2 lo = __builtin_amdgcn_cvt_pk_f32_fp8(d, false);
  f32x2 hi = __builtin_amdgcn_cvt_pk_f32_fp8(d, true);
  f[0] = lo[0]; f[1] = lo[1]; f[2] = hi[0]; f[3] = hi[1];
#else
#pragma unroll
  for (int j = 0; j < 4; ++j) f[j] = fp8tof((d >> (8 * j)) & 0xffu);
#endif
}

// ---------- weight prep + fused zeroing of out & cnt (r12 verified) ----------
__global__ __launch_bounds__(256) void prep_weights(
    const float* __restrict__ W1, const float* __restrict__ W2,
    short* __restrict__ wp, float* __restrict__ out, int outN4,
    int* __restrict__ cnt, int NN) {
  int t = blockIdx.x * 256 + threadIdx.x;
  int total = gridDim.x * 256;
  if (out) {
    f32x4* o4 = reinterpret_cast<f32x4*>(out);
    for (int i = t; i < outN4; i += total) o4[i] = (f32x4){0.f, 0.f, 0.f, 0.f};
  }
  if (cnt) {
    for (int i = t; i < NN; i += total) cnt[i] = 0;
  }
  int chunk = t >> 6, l = t & 63;
  if (chunk >= 104) return;
  int q = l >> 4, c = l & 15;
  s16x8 v;
  if (chunk < 72) {
    int kk = chunk >> 3, nt = chunk & 7;
    int k0 = kk * 32 + q * 8, n = nt * 16 + c;
#pragma unroll
    for (int j = 0; j < 8; ++j) {
      int k = k0 + j;
      v[j] = (k < 272) ? f2bf(W1[k * 128 + n]) : (short)0;
    }
    *reinterpret_cast<s16x8*>(wp + (size_t)chunk * 512 + l * 8) = v;
  } else {
    int c2 = chunk - 72;
    int kk = c2 >> 3, nt = c2 & 7;
    int k0 = kk * 32 + q * 8, n = nt * 16 + c;
#pragma unroll
    for (int j = 0; j < 8; ++j) v[j] = f2bf(W2[(k0 + j) * 128 + n]);
    *reinterpret_cast<s16x8*>(wp + 36864 + (size_t)c2 * 512 + l * 8) = v;
  }
}

// ---------- fused dense G + edge histogram (r4 verified) ----------
// G layout per node: 384 B = [128 bf16 G1 (row half)] [128 B fp8 G2 (col half, permuted)]
#define NB_H 512
__global__ __launch_bounds__(256) void k_gh(
    const float* __restrict__ h, const short* __restrict__ wp,
    short* __restrict__ Gs, const int* __restrict__ ei,
    int* __restrict__ cnt, int NN, int NB_G, int E) {
  if ((int)blockIdx.x >= NB_G) {
    int i = ((int)blockIdx.x - NB_G) * 256 + threadIdx.x;
    for (; i < E; i += NB_H * 256) atomicAdd(&cnt[ei[i]], 1);
    return;
  }
  const int tid = threadIdx.x;
  const int w = tid >> 6, l = tid & 63;
  const int q = l >> 4, c = l & 15;
  const int nb = blockIdx.x * 64 + w * 16;

  f32x4 acc[16];
#pragma unroll
  for (int nt = 0; nt < 16; ++nt) acc[nt] = (f32x4){0.f, 0.f, 0.f, 0.f};

#pragma unroll
  for (int kk = 0; kk < 4; ++kk) {
    int node = nb + c; if (node >= NN) node = NN - 1;
    const float* src = h + (size_t)node * 128 + kk * 32 + q * 8;
    s16x8 a = cvt8(*reinterpret_cast<const f4v*>(src),
                   *reinterpret_cast<const f4v*>(src + 4));
#pragma unroll
    for (int nt2 = 0; nt2 < 16; ++nt2) {
      int kkg = kk + ((nt2 >= 8) ? 4 : 0);
      int chunk = kkg * 8 + (nt2 & 7);
      s16x8 b = *reinterpret_cast<const s16x8*>(wp + (size_t)chunk * 512 + l * 8);
      acc[nt2] = MFMA_BF16(a, b, acc[nt2], 0, 0, 0);
    }
  }
  unsigned char* Gb = (unsigned char*)Gs;
#pragma unroll
  for (int nt2 = 0; nt2 < 16; ++nt2)
#pragma unroll
    for (int r = 0; r < 4; ++r) {
      int node = nb + q * 4 + r;
      if (node < NN) {
        if (nt2 < 8) {
          Gs[(size_t)node * 192 + nt2 * 16 + c] = f2bf(acc[nt2][r]);
        } else {
          int n7 = nt2 - 8;
          int addr = ((n7 & 1) * 2 + (c >> 3)) * 32 + (n7 >> 1) * 8 + (c & 7);
          Gb[(size_t)node * 384 + 256 + addr] = enc_fp8(acc[nt2][r]);
        }
      }
    }
}

// ---------- 2-phase scan (r13 verified) ----------
__global__ __launch_bounds__(1024) void k_s1(const int* __restrict__ cnt,
                                             int* __restrict__ partial, int NN) {
  __shared__ int red[16];
  int t = threadIdx.x, idx = blockIdx.x * 1024 + t;
  int v = (idx < NN) ? cnt[idx] : 0;
#pragma unroll
  for (int d = 1; d < 64; d <<= 1) v += __shfl_xor(v, d);
  if ((t & 63) == 0) red[t >> 6] = v;
  __syncthreads();
  if (t == 0) {
    int s = 0;
#pragma unroll
    for (int i = 0; i < 16; ++i) s += red[i];
    partial[blockIdx.x] = s;
  }
}
__global__ __launch_bounds__(1024) void k_s3m(int* __restrict__ cnt,
                                              const int* __restrict__ partial,
                                              int NN) {
  __shared__ int ps[1024];
  __shared__ int pbuf[64];
  __shared__ int base_s;
  int t = threadIdx.x, bid = blockIdx.x, idx = bid * 1024 + t;
  if (t < 64) pbuf[t] = (t < bid) ? partial[t] : 0;   // P <= 64 (NN <= 65536)
  int v = (idx < NN) ? cnt[idx] : 0;
  ps[t] = v;
  __syncthreads();
  if (t == 0) {
    int b = 0;
#pragma unroll
    for (int j = 0; j < 64; ++j) b += pbuf[j];
    base_s = b;
  }
  for (int d = 1; d < 1024; d <<= 1) {
    int u = (t >= d) ? ps[t - d] : 0;
    __syncthreads(); ps[t] += u; __syncthreads();
  }
  if (idx < NN) cnt[idx] = ps[t] - v + base_s;
}

// ---------- scatter v13 (r13 verified): sorted (row|col) + sorted fp8 bond ----------
__global__ void k_scatter13(const int* __restrict__ ei, int* __restrict__ cnt,
                            int* __restrict__ rc, unsigned* __restrict__ bond8,
                            const float* __restrict__ bond, int E) {
  int i = blockIdx.x * blockDim.x + threadIdx.x;
  int stride = gridDim.x * blockDim.x;
  for (; i < E; i += stride) {
    int r = ei[i], c = ei[(size_t)E + i];
    int pos = atomicAdd(&cnt[r], 1);
    rc[pos] = r | (c << 16);
    const f4v* b4 = reinterpret_cast<const f4v*>(bond + (size_t)i * 16);
    i32x4 o;
    o[0] = (int)enc_fp8x4(b4[0]);
    o[1] = (int)enc_fp8x4(b4[1]);
    o[2] = (int)enc_fp8x4(b4[2]);
    o[3] = (int)enc_fp8x4(b4[3]);
    *reinterpret_cast<i32x4*>(bond8 + (size_t)pos * 4) = o;
  }
}

// ---------- fused edge kernel v14 (r14 verified, FROZEN) ----------
// 512 thr = 8 waves x 16 sorted edges, barrier-free after weight staging.
// Weights (W1c 8KB + W2 32KB) staged once per block into LDS.
__global__ __launch_bounds__(512, 4) void edge_mlp14(
    const short* __restrict__ Gs, const int* __restrict__ rc,
    const unsigned* __restrict__ bond8, const short* __restrict__ wp,
    const float* __restrict__ b1, const float* __restrict__ b2,
    float* __restrict__ out, int E) {
  __shared__ __align__(16) char ubuf[8 * 16 * 136 * 2];   // Plds/Sred union, wave-private
  __shared__ __align__(16) short wlds[20480];             // 40 chunks x 512 shorts
  short (*Plds)[16][136] = reinterpret_cast<short(*)[16][136]>(ubuf);
  float (*Sred)[16][68]  = reinterpret_cast<float(*)[16][68]>(ubuf);

  const int tid = threadIdx.x;
  const int w = tid >> 6, l = tid & 63;
  const int q = l >> 4, c = l & 15;

  // stage weights (one contiguous 40KB copy), single barrier
  {
    const s16x8* src = reinterpret_cast<const s16x8*>(wp + 32768);
    s16x8* dst = reinterpret_cast<s16x8*>(wlds);
#pragma unroll
    for (int i = 0; i < 5; ++i) dst[tid + i * 512] = src[tid + i * 512];
  }
  __syncthreads();
  const short* wl1 = wlds;            // W1c: nt*512
  const short* wl2 = wlds + 4096;     // W2:  (kk*8+nt)*512

  // XCD-chunked bijective swizzle
  int nwg = gridDim.x;
  int qq = nwg >> 3, rr = nwg & 7;
  int xcd = blockIdx.x & 7, idx = blockIdx.x >> 3;
  int sbid = (xcd < rr ? xcd * (qq + 1) : rr * (qq + 1) + (xcd - rr) * qq) + idx;
  const int eb = sbid * 128;
  const int we = w * 16;

  // per-wave edge metadata
  int rcv = 0xFFFF;
  if (l < 16) {
    int gpos = eb + we + l;
    if (gpos < E) rcv = rc[gpos];
  }
  int v = __shfl(rcv, c);
  int rv = v & 0xffff;
  int rA = (rv == 0xFFFF) ? 0 : rv;
  int cA = ((unsigned)v) >> 16;

  int vn = __shfl(rcv, (l + 1) & 63);
  unsigned long long bm = __ballot(
      (l < 16) && ((rcv & 0xffff) != ((l < 15) ? (vn & 0xffff) : -1)));

  // hoisted gathers
  s16x8 g1v[4];
  i32x4 g2v[2];
  s16x8 az = {};
  {
    const short* gb = Gs + (size_t)rA * 192;
#pragma unroll
    for (int kk = 0; kk < 4; ++kk)
      g1v[kk] = *reinterpret_cast<const s16x8*>(gb + kk * 32 + q * 8);
    const char* g2b = (const char*)Gs + (size_t)cA * 384 + 256 + q * 32;
    g2v[0] = *reinterpret_cast<const i32x4*>(g2b);
    g2v[1] = *reinterpret_cast<const i32x4*>(g2b + 16);
    if (q < 2) {
      int ge = eb + we + c; if (ge >= E) ge = E - 1;
      uint2 d = *reinterpret_cast<const uint2*>(bond8 + (size_t)ge * 4 + q * 2);
      float f[8];
      dec_fp8x4(d.x, f);
      dec_fp8x4(d.y, f + 4);
      i32x4 aw;
#pragma unroll
      for (int p = 0; p < 4; ++p)
        aw[p] = (int)cvtpk_bf16(f[2 * p], f[2 * p + 1]);
      az = __builtin_bit_cast(s16x8, aw);
    }
  }

  // phase 1: bond @ W1c
  f32x4 acc[8];
#pragma unroll
  for (int nt = 0; nt < 8; ++nt) acc[nt] = (f32x4){0.f, 0.f, 0.f, 0.f};
  __builtin_amdgcn_s_setprio(1);
#pragma unroll
  for (int nt = 0; nt < 8; ++nt) {
    s16x8 b = *reinterpret_cast<const s16x8*>(wl1 + nt * 512 + l * 8);
    acc[nt] = MFMA_BF16(az, b, acc[nt], 0, 0, 0);
  }
  __builtin_amdgcn_s_setprio(0);

  // bridge C->A through LDS, fold b1
#pragma unroll
  for (int nt = 0; nt < 8; ++nt) {
    float bias = b1[nt * 16 + c];
    unsigned p01 = cvtpk_bf16(acc[nt][0] + bias, acc[nt][1] + bias);
    unsigned p23 = cvtpk_bf16(acc[nt][2] + bias, acc[nt][3] + bias);
    Plds[w][q * 4 + 0][nt * 16 + c] = (short)(p01 & 0xffffu);
    Plds[w][q * 4 + 1][nt * 16 + c] = (short)(p01 >> 16);
    Plds[w][q * 4 + 2][nt * 16 + c] = (short)(p23 & 0xffffu);
    Plds[w][q * 4 + 3][nt * 16 + c] = (short)(p23 >> 16);
  }

  // phase 2: GEMM2
#pragma unroll
  for (int nt = 0; nt < 8; ++nt) acc[nt] = (f32x4){0.f, 0.f, 0.f, 0.f};

#pragma unroll
  for (int kk = 0; kk < 4; ++kk) {
    s16x8 gk = g1v[kk];
    unsigned d0 = (unsigned)g2v[kk >> 1][(kk & 1) * 2 + 0];
    unsigned d1 = (unsigned)g2v[kk >> 1][(kk & 1) * 2 + 1];
    float g2f[8];
    dec_fp8x4(d0, g2f);
    dec_fp8x4(d1, g2f + 4);
    s16x8 pb = *reinterpret_cast<const s16x8*>(&Plds[w][c][kk * 32 + q * 8]);
    float sv[8];
#pragma unroll
    for (int j = 0; j < 8; ++j) {
      float x = bf2f(gk[j]) + g2f[j] + bf2f(pb[j]);
      float e = __expf(-x);
      sv[j] = x * __builtin_amdgcn_rcpf(1.f + e);
    }
    i32x4 a2w;
#pragma unroll
    for (int p = 0; p < 4; ++p)
      a2w[p] = (int)cvtpk_bf16(sv[2 * p], sv[2 * p + 1]);
    s16x8 a2 = __builtin_bit_cast(s16x8, a2w);
    __builtin_amdgcn_s_setprio(1);
#pragma unroll
    for (int nt = 0; nt < 8; ++nt) {
      s16x8 b = *reinterpret_cast<const s16x8*>(wl2 + (kk * 8 + nt) * 512 + l * 8);
      acc[nt] = MFMA_BF16(a2, b, acc[nt], 0, 0, 0);
    }
    __builtin_amdgcn_s_setprio(0);
  }

  // epilogue
#pragma unroll
  for (int h2 = 0; h2 < 2; ++h2) {
#pragma unroll
    for (int nt2 = 0; nt2 < 4; ++nt2) {
      int nt = h2 * 4 + nt2;
      float bias = b2[nt * 16 + c];
#pragma unroll
      for (int r = 0; r < 4; ++r)
        Sred[w][q * 4 + r][nt2 * 16 + c] = acc[nt][r] + bias;
    }
    float vsum = 0.f;
#pragma unroll
    for (int r = 0; r < 16; ++r) {
      vsum += Sred[w][r][l];
      if ((bm >> r) & 1ull) {
        int rowv = __shfl(rcv, r) & 0xffff;
        if (rowv != 0xFFFF)
          unsafeAtomicAdd(&out[(size_t)rowv * 128 + h2 * 64 + l], vsum);
        vsum = 0.f;
      }
    }
  }
}

// ---------- ultimate fallback (round-1 verified, wp-only) ----------
__global__ __launch_bounds__(256, 2) void edge_mlp(
    const float* __restrict__ h, const int* __restrict__ ei,
    const float* __restrict__ bond, const short* __restrict__ wp,
    const float* __restrict__ b1, const float* __restrict__ b2,
    float* __restrict__ out, int E) {
  __shared__ __align__(16) short Plds[4][64][136];
  __shared__ int rows_s[256];
  __shared__ int cols_s[256];
  const int tid = threadIdx.x;
  const int w = tid >> 6, l = tid & 63;
  const int q = l >> 4, c = l & 15;
  const int eb = blockIdx.x * 256;
  {
    int e = eb + tid; if (e >= E) e = E - 1;
    rows_s[tid] = ei[e];
    cols_s[tid] = ei[(size_t)E + e];
  }
  __syncthreads();
  const int we = w * 64;
  int rN[4], cN[4], eI[4];
#pragma unroll
  for (int mi = 0; mi < 4; ++mi) {
    int el = we + mi * 16 + c;
    rN[mi] = rows_s[el]; cN[mi] = cols_s[el];
    int eg = eb + el; if (eg >= E) eg = E - 1;
    eI[mi] = eg;
  }
  f32x4 acc[4][8];
#pragma unroll
  for (int mi = 0; mi < 4; ++mi)
#pragma unroll
    for (int nt = 0; nt < 8; ++nt) acc[mi][nt] = (f32x4){0.f, 0.f, 0.f, 0.f};
#pragma unroll
  for (int part = 0; part < 2; ++part) {
#pragma unroll
    for (int kk = 0; kk < 4; ++kk) {
      s16x8 a[4];
#pragma unroll
      for (int mi = 0; mi < 4; ++mi) {
        int node = part ? cN[mi] : rN[mi];
        const float* src = h + (size_t)node * 128 + kk * 32 + q * 8;
        a[mi] = cvt8(*reinterpret_cast<const f4v*>(src),
                     *reinterpret_cast<const f4v*>(src + 4));
      }
      const int kkg = part * 4 + kk;
#pragma unroll
      for (int nt = 0; nt < 8; ++nt) {
        s16x8 b = *reinterpret_cast<const s16x8*>(wp + (size_t)(kkg * 8 + nt) * 512 + l * 8);
#pragma unroll
        for (int mi = 0; mi < 4; ++mi)
          acc[mi][nt] = MFMA_BF16(a[mi], b, acc[mi][nt], 0, 0, 0);
      }
    }
  }
  {
    s16x8 a[4];
#pragma unroll
    for (int mi = 0; mi < 4; ++mi) {
      s16x8 az = {};
      if (q < 2) {
        const float* src = bond + (size_t)eI[mi] * 16 + q * 8;
        az = cvt8(*reinterpret_cast<const f4v*>(src),
                  *reinterpret_cast<const f4v*>(src + 4));
      }
      a[mi] = az;
    }
#pragma unroll
    for (int nt = 0; nt < 8; ++nt) {
      s16x8 b = *reinterpret_cast<const s16x8*>(wp + (size_t)(64 + nt) * 512 + l * 8);
#pragma unroll
      for (int mi = 0; mi < 4; ++mi)
        acc[mi][nt] = MFMA_BF16(a[mi], b, acc[mi][nt], 0, 0, 0);
    }
  }
#pragma unroll
  for (int nt = 0; nt < 8; ++nt) {
    float bias = b1[nt * 16 + c];
#pragma unroll
    for (int mi = 0; mi < 4; ++mi)
#pragma unroll
      for (int r = 0; r < 4; ++r) {
        float x = acc[mi][nt][r] + bias;
        float s = x / (1.f + __expf(-x));
        Plds[w][mi * 16 + q * 4 + r][nt * 16 + c] = f2bf(s);
      }
  }
  f32x4 acc2[4][8];
#pragma unroll
  for (int mi = 0; mi < 4; ++mi)
#pragma unroll
    for (int nt = 0; nt < 8; ++nt) acc2[mi][nt] = (f32x4){0.f, 0.f, 0.f, 0.f};
#pragma unroll
  for (int kk = 0; kk < 4; ++kk) {
    s16x8 a2[4];
#pragma unroll
    for (int mi = 0; mi < 4; ++mi)
      a2[mi] = *reinterpret_cast<const s16x8*>(&Plds[w][mi * 16 + c][kk * 32 + q * 8]);
#pragma unroll
    for (int nt = 0; nt < 8; ++nt) {
      s16x8 b = *reinterpret_cast<const s16x8*>(wp + 36864 + (size_t)(kk * 8 + nt) * 512 + l * 8);
#pragma unroll
      for (int mi = 0; mi < 4; ++mi)
        acc2[mi][nt] = MFMA_BF16(a2[mi], b, acc2[mi][nt], 0, 0, 0);
    }
  }
#pragma unroll
  for (int nt = 0; nt < 8; ++nt) {
    float bias = b2[nt * 16 + c];
#pragma unroll
    for (int mi = 0; mi < 4; ++mi)
#pragma unroll
      for (int r = 0; r < 4; ++r) {
        int el = we + mi * 16 + q * 4 + r;
        if ((eb + el) < E) {
          int node = rows_s[el];
          unsafeAtomicAdd(&out[(size_t)node * 128 + nt * 16 + c],
                          acc2[mi][nt][r] + bias);
        }
      }
  }
}

extern "C" void kernel_launch(void* const* d_in, const int* in_sizes, int n_in,
                              void* d_out, int out_size, void* d_ws, size_t ws_size,
                              hipStream_t stream) {
  const float* h    = (const float*)d_in[0];
  const int*   ei   = (const int*)d_in[1];
  const float* bond = (const float*)d_in[2];
  const float* W1   = (const float*)d_in[3];
  const float* b1   = (const float*)d_in[4];
  const float* W2   = (const float*)d_in[5];
  const float* b2   = (const float*)d_in[6];
  float* out = (float*)d_out;
  char* ws = (char*)d_ws;

  const int E  = in_sizes[1] / 2;
  const int NN = in_sizes[0] / 128;

  // ws layout (bytes, 16-aligned)
  short* wp = (short*)ws;                                   // 131072
  size_t off_G    = 131072;
  size_t off_cnt  = off_G + (size_t)NN * 384;
  size_t off_par  = off_cnt + (((size_t)NN * 4 + 15) & ~15ull);
  size_t off_idx  = off_par + 4096;
  size_t off_bs   = off_idx + (((size_t)E * 4 + 15) & ~15ull);
  size_t need14   = off_bs + (size_t)E * 16;                // fp8 sorted bond

  if (ws_size >= need14 && NN <= 65535) {
    short*    Gs    = (short*)(ws + off_G);
    int*      cnt   = (int*)(ws + off_cnt);
    int*      par   = (int*)(ws + off_par);
    int*      rc    = (int*)(ws + off_idx);
    unsigned* bond8 = (unsigned*)(ws + off_bs);
    const int NB_G = (NN + 63) / 64;
    const int P    = (NN + 1023) / 1024;

    prep_weights<<<512, 256, 0, stream>>>(W1, W2, wp, out, NN * 32, cnt, NN);
    k_gh<<<NB_G + NB_H, 256, 0, stream>>>(h, wp, Gs, ei, cnt, NN, NB_G, E);
    k_s1<<<P, 1024, 0, stream>>>(cnt, par, NN);
    k_s3m<<<P, 1024, 0, stream>>>(cnt, par, NN);
    k_scatter13<<<2048, 256, 0, stream>>>(ei, cnt, rc, bond8, bond, E);
    edge_mlp14<<<(E + 127) / 128, 512, 0, stream>>>(Gs, rc, bond8, wp, b1, b2, out, E);
  } else {
    hipMemsetAsync(d_out, 0, (size_t)NN * 128 * sizeof(float), stream);
    prep_weights<<<512, 256, 0, stream>>>(W1, W2, wp, (float*)nullptr, 0,
                                          (int*)nullptr, 0);
    edge_mlp<<<(E + 255) / 256, 256, 0, stream>>>(h, ei, bond, wp, b1, b2, out, E);
  }
}